// Round 1
// baseline (179.530 us; speedup 1.0000x reference)
//
#include <hip/hip_runtime.h>
#include <hip/hip_bf16.h>

#define B_  2
#define T_  2048
#define D_  1024
#define H_  16
#define DH_ 64
#define M_  (B_*T_)   // 4096

typedef _Float16 f16;
typedef __attribute__((ext_vector_type(4))) _Float16 f16x4;
typedef __attribute__((ext_vector_type(8))) _Float16 f16x8;
typedef __attribute__((ext_vector_type(4))) float f32x4;

// async global->LDS, 16B per lane; LDS dest must be wave-uniform-base + lane*16
#define GLOAD_LDS(gp, lp) __builtin_amdgcn_global_load_lds( \
    (const __attribute__((address_space(1))) void*)(gp),    \
    (__attribute__((address_space(3))) void*)(lp), 16, 0, 0)

// ---------------- prep: x fp32->fp16 convert + 4 weight transposes, one launch ----------------
// blocks [0,2048): cvt x (256 thr * 8 elts); blocks [2048,6144): 32x32 transpose tiles
__global__ void prep(const float* __restrict__ x,
                     const float* __restrict__ wq, const float* __restrict__ wk,
                     const float* __restrict__ wv, const float* __restrict__ wo,
                     f16* __restrict__ xb, f16* __restrict__ wqkvT, f16* __restrict__ woutT) {
  __shared__ float tile[32][33];
  const int bid = blockIdx.x;
  if (bid < 2048) {
    size_t i = ((size_t)bid * 256 + threadIdx.x) * 8;
    float4 a = *(const float4*)(x + i);
    float4 b = *(const float4*)(x + i + 4);
    f16x8 o;
    o[0]=(f16)a.x; o[1]=(f16)a.y; o[2]=(f16)a.z; o[3]=(f16)a.w;
    o[4]=(f16)b.x; o[5]=(f16)b.y; o[6]=(f16)b.z; o[7]=(f16)b.w;
    *(f16x8*)(xb + i) = o;
  } else {
    const int b2 = bid - 2048;
    const int j = b2 >> 10, rem = b2 & 1023;
    const float* src = (j==0)?wq:(j==1)?wk:(j==2)?wv:wo;
    f16* dst = (j<3) ? (wqkvT + (size_t)j*D_*D_) : woutT;
    const int n0 = (rem & 31)*32, k0 = (rem >> 5)*32;
    const int tx = threadIdx.x & 31, ty = threadIdx.x >> 5;  // (32,8)
    #pragma unroll
    for (int i=0;i<32;i+=8)
      tile[ty+i][tx] = src[(size_t)(k0+ty+i)*D_ + n0+tx];
    __syncthreads();
    #pragma unroll
    for (int i=0;i<32;i+=8)
      dst[(size_t)(n0+ty+i)*D_ + k0+tx] = (f16)tile[tx][ty+i];
  }
}

// ---------------- QKV projection GEMM: dbuf K-loop + XCD swizzle ----------------
__launch_bounds__(256, 2)
__global__ void qkv_gemm(const f16* __restrict__ xb, const f16* __restrict__ wT,
                         f16* __restrict__ Qp, f16* __restrict__ Kp, f16* __restrict__ Vtp) {
  const int fid = blockIdx.x;
  const int g = fid & 7, r = fid >> 3;
  const int m0 = ((((r & 3) << 3) | g)) * 128;   // 32 m-blocks; m-block % 8 == XCD
  const int n0 = ((r >> 2) & 7) * 128;           // 8 n-blocks
  const int j  = r >> 5;                         // 0..2
  const f16* B0 = wT + (size_t)j * D_ * D_;
  __shared__ alignas(16) char smem[65536];       // As[2]|Bs[2] = 64 KB; VtS reuses front
  f16* AsF = (f16*)smem;             // [2][128*64]
  f16* BsF = AsF + 2*128*64;         // [2][128*64]
  const int tid = threadIdx.x;
  const int lane = tid & 63, wave = tid >> 6;
  const int ln = lane & 15, quad = lane >> 4;
  const int wm = wave >> 1, wn = wave & 1;

  f32x4 acc[4][4];
  #pragma unroll
  for (int a=0;a<4;++a)
    #pragma unroll
    for (int b=0;b<4;++b) acc[a][b] = f32x4{0.f,0.f,0.f,0.f};

  const bool swapped = (j < 2);
  const int slot_row[4] = { (0*256+tid)>>3, (1*256+tid)>>3, (2*256+tid)>>3, (3*256+tid)>>3 };

  #pragma unroll
  for (int p = 0; p < 4; ++p) {
    int slot = p*256 + tid;
    int row  = slot_row[p];
    int c    = (slot & 7) ^ (row & 7);
    GLOAD_LDS(xb + (size_t)(m0+row)*D_ + c*8, AsF + (size_t)slot*8);
    GLOAD_LDS(B0 + (size_t)(n0+row)*D_ + c*8, BsF + (size_t)slot*8);
  }
  __syncthreads();

  for (int it = 0; it < 16; ++it) {
    const f16* Ac = AsF + (it & 1)*8192;
    const f16* Bc = BsF + (it & 1)*8192;
    if (it < 15) {   // async-prefetch next k-tile into other buffer
      const int k1 = (it + 1) * 64;
      f16* An = AsF + ((it + 1) & 1)*8192;
      f16* Bn = BsF + ((it + 1) & 1)*8192;
      #pragma unroll
      for (int p = 0; p < 4; ++p) {
        int slot = p*256 + tid;
        int row  = slot_row[p];
        int c    = (slot & 7) ^ (row & 7);
        GLOAD_LDS(xb + (size_t)(m0+row)*D_ + k1 + c*8, An + (size_t)slot*8);
        GLOAD_LDS(B0 + (size_t)(n0+row)*D_ + k1 + c*8, Bn + (size_t)slot*8);
      }
    }
    #pragma unroll
    for (int ks = 0; ks < 2; ++ks) {
      const int cb = ((ks*4 + quad) ^ (ln & 7)) * 8;
      f16x8 af[4], bf[4];
      #pragma unroll
      for (int mt = 0; mt < 4; ++mt)
        af[mt] = *(const f16x8*)(Ac + (size_t)(wm*64 + mt*16 + ln)*64 + cb);
      #pragma unroll
      for (int nt = 0; nt < 4; ++nt)
        bf[nt] = *(const f16x8*)(Bc + (size_t)(wn*64 + nt*16 + ln)*64 + cb);
      if (swapped) {
        #pragma unroll
        for (int nt = 0; nt < 4; ++nt)
          #pragma unroll
          for (int mt = 0; mt < 4; ++mt)
            acc[nt][mt] = __builtin_amdgcn_mfma_f32_16x16x32_f16(bf[nt], af[mt], acc[nt][mt], 0, 0, 0);
      } else {
        #pragma unroll
        for (int mt = 0; mt < 4; ++mt)
          #pragma unroll
          for (int nt = 0; nt < 4; ++nt)
            acc[mt][nt] = __builtin_amdgcn_mfma_f32_16x16x32_f16(af[mt], bf[nt], acc[mt][nt], 0, 0, 0);
      }
    }
    __syncthreads();   // drains vmcnt(0): prefetch done; all reads of Ac/Bc done
  }

  if (swapped) {
    // C^T: row n = wn*64+nt*16+quad*4+r (feature), col m = wm*64+mt*16+ln (token)
    const float scale = (j == 0) ? 0.125f : 1.0f;
    f16* dstB = (j == 0) ? Qp : Kp;
    #pragma unroll
    for (int nt = 0; nt < 4; ++nt)
      #pragma unroll
      for (int mt = 0; mt < 4; ++mt) {
        int gm = m0 + wm*64 + mt*16 + ln;            // token
        int gn = n0 + wn*64 + nt*16 + quad*4;        // feature (base of 4)
        int bb = gm >> 11, t = gm & (T_-1);
        int h  = gn >> 6,  dd = gn & (DH_-1);
        f16x4 v;
        #pragma unroll
        for (int rr = 0; rr < 4; ++rr) v[rr] = (f16)(acc[nt][mt][rr] * scale);
        *(f16x4*)&dstB[((((size_t)bb*H_ + h)*T_ + t)*DH_) + dd] = v;
      }
  } else {
    // V -> [b,h,d,t] via LDS transpose bounce (coalesced 128B global stores)
    f16* VtS = (f16*)smem;              // [128][136] = 34816 B, safe after final barrier
    #pragma unroll
    for (int mt = 0; mt < 4; ++mt)
      #pragma unroll
      for (int nt = 0; nt < 4; ++nt) {
        f16x4 v;
        v[0]=(f16)acc[mt][nt][0]; v[1]=(f16)acc[mt][nt][1];
        v[2]=(f16)acc[mt][nt][2]; v[3]=(f16)acc[mt][nt][3];
        *(f16x4*)&VtS[(size_t)(wn*64 + nt*16 + ln)*136 + wm*64 + mt*16 + quad*4] = v;
      }
    __syncthreads();
    int dd_loc = tid >> 1, half = tid & 1;
    int gn = n0 + dd_loc, h = gn >> 6, dd = gn & (DH_-1);
    int bb = m0 >> 11, tb = (m0 & (T_-1)) + half*64;
    f16* dst = Vtp + ((size_t)(bb*H_ + h)*DH_ + dd)*T_ + tb;
    const f16* src = VtS + (size_t)dd_loc*136 + half*64;
    #pragma unroll
    for (int u = 0; u < 8; ++u)
      *(uint4*)(dst + u*8) = *(const uint4*)(src + u*8);
  }
}

// ---------------- flash attention: BQ=128 per block, 4 waves x 2 q-groups of 16 ----------------
// grid 512: bh = fid & 31 (same head -> same XCD), qt = 15 - (fid >> 5) (heavy first).
// Each wave owns 32 q-rows (two 16-row groups sharing K/V fragment loads).
// S^T no-max softmax, wave-private P, async dbuf K/V (64-row tiles).
__launch_bounds__(256, 3)
__global__ void flash(const f16* __restrict__ Qp, const f16* __restrict__ Kp,
                      const f16* __restrict__ Vtp, f16* __restrict__ ctx) {
  const int fid = blockIdx.x;
  const int bh = fid & 31;
  const int qt = 15 - (fid >> 5);       // 0..15, heavy first
  const int b = bh >> 4, h = bh & (H_-1);
  const f16* Kh = Kp  + (size_t)bh * T_ * DH_;
  const f16* Vh = Vtp + (size_t)bh * DH_ * T_;
  const f16* Qh = Qp  + (size_t)bh * T_ * DH_;
  const int tid = threadIdx.x, lane = tid & 63, w = tid >> 6;
  const int ln = lane & 15, quad = lane >> 4;
  __shared__ alignas(16) f16 Ks[2*64*64];   // dbuf, XOR-swizzled 16B blocks
  __shared__ alignas(16) f16 Vs[2*64*64];
  __shared__ alignas(16) f16 Ps[128][72];

  const int qw0 = qt*128 + w*32;            // group g covers rows qw0+g*16 .. +15

  f16x8 qf[2][2];
  #pragma unroll
  for (int gq = 0; gq < 2; ++gq)
    #pragma unroll
    for (int ks = 0; ks < 2; ++ks)
      qf[gq][ks] = *(const f16x8*)&Qh[(size_t)(qw0 + gq*16 + ln)*DH_ + ks*32 + quad*8];

  f32x4 o[2][4];
  #pragma unroll
  for (int gq = 0; gq < 2; ++gq)
    #pragma unroll
    for (int dt = 0; dt < 4; ++dt) o[gq][dt] = f32x4{0.f,0.f,0.f,0.f};
  float l_part0 = 0.f, l_part1 = 0.f;

  const int it_max = 2*qt + 1;

  // prologue: stage kv tile 0 into buffer 0 (256 threads, 2 slots each per array)
  #pragma unroll
  for (int i = 0; i < 2; ++i) {
    int slot = i*256 + tid;
    int row  = slot >> 3;
    int c    = (slot & 7) ^ (row & 7);
    GLOAD_LDS(Kh + (size_t)row*DH_ + c*8, Ks + (size_t)slot*8);
    GLOAD_LDS(Vh + (size_t)row*T_  + c*8, Vs + (size_t)slot*8);
  }
  __syncthreads();

  for (int it = 0; it <= it_max; ++it) {
    const f16* Kc = Ks + (it & 1)*4096;
    const f16* Vc = Vs + (it & 1)*4096;
    if (it < it_max) {    // async-prefetch next tile into other buffer
      const int kv1 = (it + 1)*64;
      f16* Kn = Ks + ((it + 1) & 1)*4096;
      f16* Vn = Vs + ((it + 1) & 1)*4096;
      #pragma unroll
      for (int i = 0; i < 2; ++i) {
        int slot = i*256 + tid;
        int row  = slot >> 3;
        int c    = (slot & 7) ^ (row & 7);
        GLOAD_LDS(Kh + (size_t)(kv1 + row)*DH_ + c*8, Kn + (size_t)slot*8);
        GLOAD_LDS(Vh + (size_t)row*T_ + kv1 + c*8,    Vn + (size_t)slot*8);
      }
    }
    const int kv0 = it*64;

    // S^T[kv][q] = mfma(K rows, Q rows); both q-groups share kx loads
    f32x4 s[2][4];
    #pragma unroll
    for (int gq = 0; gq < 2; ++gq)
      #pragma unroll
      for (int kt = 0; kt < 4; ++kt) s[gq][kt] = f32x4{0.f,0.f,0.f,0.f};
    #pragma unroll
    for (int ks = 0; ks < 2; ++ks) {
      f16x8 kx[4];
      #pragma unroll
      for (int kt = 0; kt < 4; ++kt)
        kx[kt] = *(const f16x8*)(Kc + (size_t)(kt*16 + ln)*64 + (((ks*4 + quad) ^ (ln & 7))*8));
      #pragma unroll
      for (int kt = 0; kt < 4; ++kt) {
        s[0][kt] = __builtin_amdgcn_mfma_f32_16x16x32_f16(kx[kt], qf[0][ks], s[0][kt], 0, 0, 0);
        s[1][kt] = __builtin_amdgcn_mfma_f32_16x16x32_f16(kx[kt], qf[1][ks], s[1][kt], 0, 0, 0);
      }
    }

    // causal mask + exp + P -> LDS, per q-group (fully-masked groups give exp(-inf)=0)
    #pragma unroll
    for (int gq = 0; gq < 2; ++gq) {
      const int qwg = qw0 + gq*16;
      if (kv0 + 63 > qwg) {
        #pragma unroll
        for (int kt = 0; kt < 4; ++kt)
          #pragma unroll
          for (int rr = 0; rr < 4; ++rr)
            if (kv0 + kt*16 + quad*4 + rr > qwg + ln) s[gq][kt][rr] = -INFINITY;
      }
      #pragma unroll
      for (int kt = 0; kt < 4; ++kt) {
        f16x4 pk;
        #pragma unroll
        for (int rr = 0; rr < 4; ++rr) {
          float pe = __expf(s[gq][kt][rr]);
          if (gq == 0) l_part0 += pe; else l_part1 += pe;
          pk[rr] = (f16)pe;
        }
        *(f16x4*)&Ps[w*32 + gq*16 + ln][kt*16 + quad*4] = pk;
      }
    }
    asm volatile("" ::: "memory");  // same-wave ds_write -> ds_read order

    // O[q][d] += mfma(P rows q, V^T rows d); vy loads shared across q-groups
    #pragma unroll
    for (int ks = 0; ks < 2; ++ks) {
      f16x8 px0 = *(const f16x8*)&Ps[w*32 + ln][ks*32 + quad*8];
      f16x8 px1 = *(const f16x8*)&Ps[w*32 + 16 + ln][ks*32 + quad*8];
      #pragma unroll
      for (int dt = 0; dt < 4; ++dt) {
        f16x8 vy = *(const f16x8*)(Vc + (size_t)(dt*16 + ln)*64 + (((ks*4 + quad) ^ (ln & 7))*8));
        o[0][dt] = __builtin_amdgcn_mfma_f32_16x16x32_f16(px0, vy, o[0][dt], 0, 0, 0);
        o[1][dt] = __builtin_amdgcn_mfma_f32_16x16x32_f16(px1, vy, o[1][dt], 0, 0, 0);
      }
    }
    __syncthreads();     // drains vmcnt(0): prefetched tile complete; bufs safe to swap
  }

  // denominator reduce (2 shuffles per group) + normalize + write
  #pragma unroll
  for (int gq = 0; gq < 2; ++gq) {
    float l = (gq == 0) ? l_part0 : l_part1;
    l += __shfl_xor(l, 16, 64);
    l += __shfl_xor(l, 32, 64);
    float inv = 1.0f / l;
    #pragma unroll
    for (int rr = 0; rr < 4; ++rr) {
      float linv = __shfl(inv, quad*4 + rr, 64);
      int t = qt*128 + w*32 + gq*16 + quad*4 + rr;
      #pragma unroll
      for (int dt = 0; dt < 4; ++dt)
        ctx[(size_t)(b*T_ + t)*D_ + h*DH_ + dt*16 + ln] = (f16)(o[gq][dt][rr] * linv);
    }
  }
}

// ---------------- output projection GEMM + bias: dbuf + XCD swizzle ----------------
__launch_bounds__(256, 2)
__global__ void out_gemm(const f16* __restrict__ ctx, const f16* __restrict__ woT,
                         const float* __restrict__ bo, float* __restrict__ out) {
  const int fid = blockIdx.x;             // [0,256)
  const int g = fid & 7, r = fid >> 3;
  const int m0 = ((((r & 3) << 3) | g)) * 128;   // m-block % 8 == XCD
  const int n0 = (r >> 2) * 128;
  __shared__ alignas(16) f16 smem[4*128*64];     // As[2]|Bs[2]
  f16* AsF = smem;
  f16* BsF = AsF + 2*128*64;
  const int tid = threadIdx.x;
  const int lane = tid & 63, wave = tid >> 6;
  const int ln = lane & 15, quad = lane >> 4;
  const int wm = wave >> 1, wn = wave & 1;

  f32x4 acc[4][4];   // [nt][mt], C^T layout
  #pragma unroll
  for (int a=0;a<4;++a)
    #pragma unroll
    for (int b=0;b<4;++b) acc[a][b] = f32x4{0.f,0.f,0.f,0.f};

  #pragma unroll
  for (int p = 0; p < 4; ++p) {
    int slot = p*256 + tid;
    int row  = slot >> 3;
    int c    = (slot & 7) ^ (row & 7);
    GLOAD_LDS(ctx + (size_t)(m0+row)*D_ + c*8, AsF + (size_t)slot*8);
    GLOAD_LDS(woT + (size_t)(n0+row)*D_ + c*8, BsF + (size_t)slot*8);
  }
  __syncthreads();

  for (int it = 0; it < 16; ++it) {
    const f16* Ac = AsF + (it & 1)*8192;
    const f16* Bc = BsF + (it & 1)*8192;
    if (it < 15) {
      const int k1 = (it + 1) * 64;
      f16* An = AsF + ((it + 1) & 1)*8192;
      f16* Bn = BsF + ((it + 1) & 1)*8192;
      #pragma unroll
      for (int p = 0; p < 4; ++p) {
        int slot = p*256 + tid;
        int row  = slot >> 3;
        int c    = (slot & 7) ^ (row & 7);
        GLOAD_LDS(ctx + (size_t)(m0+row)*D_ + k1 + c*8, An + (size_t)slot*8);
        GLOAD_LDS(woT + (size_t)(n0+row)*D_ + k1 + c*8, Bn + (size_t)slot*8);
      }
    }
    #pragma unroll
    for (int ks = 0; ks < 2; ++ks) {
      const int cb = ((ks*4 + quad) ^ (ln & 7)) * 8;
      f16x8 af[4], bf[4];
      #pragma unroll
      for (int mt = 0; mt < 4; ++mt)
        af[mt] = *(const f16x8*)(Ac + (size_t)(wm*64 + mt*16 + ln)*64 + cb);
      #pragma unroll
      for (int nt = 0; nt < 4; ++nt)
        bf[nt] = *(const f16x8*)(Bc + (size_t)(wn*64 + nt*16 + ln)*64 + cb);
      #pragma unroll
      for (int nt = 0; nt < 4; ++nt)
        #pragma unroll
        for (int mt = 0; mt < 4; ++mt)
          acc[nt][mt] = __builtin_amdgcn_mfma_f32_16x16x32_f16(bf[nt], af[mt], acc[nt][mt], 0, 0, 0);
    }
    __syncthreads();
  }

  #pragma unroll
  for (int nt = 0; nt < 4; ++nt) {
    int gn = n0 + wn*64 + nt*16 + quad*4;
    float4 bv = *(const float4*)&bo[gn];
    #pragma unroll
    for (int mt = 0; mt < 4; ++mt) {
      int gm = m0 + wm*64 + mt*16 + ln;
      float4 v;
      v.x = acc[nt][mt][0] + bv.x;
      v.y = acc[nt][mt][1] + bv.y;
      v.z = acc[nt][mt][2] + bv.z;
      v.w = acc[nt][mt][3] + bv.w;
      *(float4*)&out[(size_t)gm*D_ + gn] = v;
    }
  }
}

extern "C" void kernel_launch(void* const* d_in, const int* in_sizes, int n_in,
                              void* d_out, int out_size, void* d_ws, size_t ws_size,
                              hipStream_t stream) {
  const float* x  = (const float*)d_in[0];
  const float* wq = (const float*)d_in[1];
  const float* wk = (const float*)d_in[2];
  const float* wv = (const float*)d_in[3];
  const float* wo = (const float*)d_in[4];
  const float* bo = (const float*)d_in[5];
  float* out = (float*)d_out;

  f16* ws    = (f16*)d_ws;
  f16* xb    = ws;                         // M_*D_
  f16* wqkvT = xb    + (size_t)M_*D_;      // 3*D_*D_
  f16* woutT = wqkvT + (size_t)3*D_*D_;    // D_*D_
  f16* Qb    = woutT + (size_t)D_*D_;      // M_*D_  ([b,h,t,d], pre-scaled)
  f16* Kb    = Qb    + (size_t)M_*D_;      // M_*D_  ([b,h,t,d])
  f16* Vb    = Kb    + (size_t)M_*D_;      // M_*D_  ([b,h,d,t])
  f16* ctx   = Vb    + (size_t)M_*D_;      // M_*D_  ([b*t, h*d])

  prep<<<6144, 256, 0, stream>>>(x, wq, wk, wv, wo, xb, wqkvT, woutT);
  qkv_gemm<<<768, 256, 0, stream>>>(xb, wqkvT, Qb, Kb, Vb);
  flash<<<512, 256, 0, stream>>>(Qb, Kb, Vb, ctx);
  out_gemm<<<256, 256, 0, stream>>>(ctx, woutT, bo, out);
}

// Round 2
// 177.636 us; speedup vs baseline: 1.0107x; 1.0107x over previous
//
#include <hip/hip_runtime.h>
#include <hip/hip_bf16.h>

#define B_  2
#define T_  2048
#define D_  1024
#define H_  16
#define DH_ 64
#define M_  (B_*T_)   // 4096

typedef _Float16 f16;
typedef __attribute__((ext_vector_type(4))) _Float16 f16x4;
typedef __attribute__((ext_vector_type(8))) _Float16 f16x8;
typedef __attribute__((ext_vector_type(4))) float f32x4;

// async global->LDS, 16B per lane; LDS dest must be wave-uniform-base + lane*16
#define GLOAD_LDS(gp, lp) __builtin_amdgcn_global_load_lds( \
    (const __attribute__((address_space(1))) void*)(gp),    \
    (__attribute__((address_space(3))) void*)(lp), 16, 0, 0)

// ---------------- prep: x fp32->fp16 convert + 4 weight transposes, one launch ----------------
// blocks [0,2048): cvt x (256 thr * 8 elts); blocks [2048,6144): 32x32 transpose tiles
__global__ void prep(const float* __restrict__ x,
                     const float* __restrict__ wq, const float* __restrict__ wk,
                     const float* __restrict__ wv, const float* __restrict__ wo,
                     f16* __restrict__ xb, f16* __restrict__ wqkvT, f16* __restrict__ woutT) {
  __shared__ float tile[32][33];
  const int bid = blockIdx.x;
  if (bid < 2048) {
    size_t i = ((size_t)bid * 256 + threadIdx.x) * 8;
    float4 a = *(const float4*)(x + i);
    float4 b = *(const float4*)(x + i + 4);
    f16x8 o;
    o[0]=(f16)a.x; o[1]=(f16)a.y; o[2]=(f16)a.z; o[3]=(f16)a.w;
    o[4]=(f16)b.x; o[5]=(f16)b.y; o[6]=(f16)b.z; o[7]=(f16)b.w;
    *(f16x8*)(xb + i) = o;
  } else {
    const int b2 = bid - 2048;
    const int j = b2 >> 10, rem = b2 & 1023;
    const float* src = (j==0)?wq:(j==1)?wk:(j==2)?wv:wo;
    f16* dst = (j<3) ? (wqkvT + (size_t)j*D_*D_) : woutT;
    const int n0 = (rem & 31)*32, k0 = (rem >> 5)*32;
    const int tx = threadIdx.x & 31, ty = threadIdx.x >> 5;  // (32,8)
    #pragma unroll
    for (int i=0;i<32;i+=8)
      tile[ty+i][tx] = src[(size_t)(k0+ty+i)*D_ + n0+tx];
    __syncthreads();
    #pragma unroll
    for (int i=0;i<32;i+=8)
      dst[(size_t)(n0+ty+i)*D_ + k0+tx] = (f16)tile[tx][ty+i];
  }
}

// ---------------- QKV projection GEMM: dbuf K-loop + XCD swizzle ----------------
__launch_bounds__(256, 2)
__global__ void qkv_gemm(const f16* __restrict__ xb, const f16* __restrict__ wT,
                         f16* __restrict__ Qp, f16* __restrict__ Kp, f16* __restrict__ Vtp) {
  const int fid = blockIdx.x;
  const int g = fid & 7, r = fid >> 3;
  const int m0 = ((((r & 3) << 3) | g)) * 128;   // 32 m-blocks; m-block % 8 == XCD
  const int n0 = ((r >> 2) & 7) * 128;           // 8 n-blocks
  const int j  = r >> 5;                         // 0..2
  const f16* B0 = wT + (size_t)j * D_ * D_;
  __shared__ alignas(16) char smem[65536];       // As[2]|Bs[2] = 64 KB; VtS reuses front
  f16* AsF = (f16*)smem;             // [2][128*64]
  f16* BsF = AsF + 2*128*64;         // [2][128*64]
  const int tid = threadIdx.x;
  const int lane = tid & 63, wave = tid >> 6;
  const int ln = lane & 15, quad = lane >> 4;
  const int wm = wave >> 1, wn = wave & 1;

  f32x4 acc[4][4];
  #pragma unroll
  for (int a=0;a<4;++a)
    #pragma unroll
    for (int b=0;b<4;++b) acc[a][b] = f32x4{0.f,0.f,0.f,0.f};

  const bool swapped = (j < 2);
  const int slot_row[4] = { (0*256+tid)>>3, (1*256+tid)>>3, (2*256+tid)>>3, (3*256+tid)>>3 };

  #pragma unroll
  for (int p = 0; p < 4; ++p) {
    int slot = p*256 + tid;
    int row  = slot_row[p];
    int c    = (slot & 7) ^ (row & 7);
    GLOAD_LDS(xb + (size_t)(m0+row)*D_ + c*8, AsF + (size_t)slot*8);
    GLOAD_LDS(B0 + (size_t)(n0+row)*D_ + c*8, BsF + (size_t)slot*8);
  }
  __syncthreads();

  for (int it = 0; it < 16; ++it) {
    const f16* Ac = AsF + (it & 1)*8192;
    const f16* Bc = BsF + (it & 1)*8192;
    if (it < 15) {   // async-prefetch next k-tile into other buffer
      const int k1 = (it + 1) * 64;
      f16* An = AsF + ((it + 1) & 1)*8192;
      f16* Bn = BsF + ((it + 1) & 1)*8192;
      #pragma unroll
      for (int p = 0; p < 4; ++p) {
        int slot = p*256 + tid;
        int row  = slot_row[p];
        int c    = (slot & 7) ^ (row & 7);
        GLOAD_LDS(xb + (size_t)(m0+row)*D_ + k1 + c*8, An + (size_t)slot*8);
        GLOAD_LDS(B0 + (size_t)(n0+row)*D_ + k1 + c*8, Bn + (size_t)slot*8);
      }
    }
    #pragma unroll
    for (int ks = 0; ks < 2; ++ks) {
      const int cb = ((ks*4 + quad) ^ (ln & 7)) * 8;
      f16x8 af[4], bf[4];
      #pragma unroll
      for (int mt = 0; mt < 4; ++mt)
        af[mt] = *(const f16x8*)(Ac + (size_t)(wm*64 + mt*16 + ln)*64 + cb);
      #pragma unroll
      for (int nt = 0; nt < 4; ++nt)
        bf[nt] = *(const f16x8*)(Bc + (size_t)(wn*64 + nt*16 + ln)*64 + cb);
      if (swapped) {
        #pragma unroll
        for (int nt = 0; nt < 4; ++nt)
          #pragma unroll
          for (int mt = 0; mt < 4; ++mt)
            acc[nt][mt] = __builtin_amdgcn_mfma_f32_16x16x32_f16(bf[nt], af[mt], acc[nt][mt], 0, 0, 0);
      } else {
        #pragma unroll
        for (int mt = 0; mt < 4; ++mt)
          #pragma unroll
          for (int nt = 0; nt < 4; ++nt)
            acc[mt][nt] = __builtin_amdgcn_mfma_f32_16x16x32_f16(af[mt], bf[nt], acc[mt][nt], 0, 0, 0);
      }
    }
    __syncthreads();   // drains vmcnt(0): prefetch done; all reads of Ac/Bc done
  }

  if (swapped) {
    // C^T: row n = wn*64+nt*16+quad*4+r (feature), col m = wm*64+mt*16+ln (token)
    const float scale = (j == 0) ? 0.125f : 1.0f;
    f16* dstB = (j == 0) ? Qp : Kp;
    #pragma unroll
    for (int nt = 0; nt < 4; ++nt)
      #pragma unroll
      for (int mt = 0; mt < 4; ++mt) {
        int gm = m0 + wm*64 + mt*16 + ln;            // token
        int gn = n0 + wn*64 + nt*16 + quad*4;        // feature (base of 4)
        int bb = gm >> 11, t = gm & (T_-1);
        int h  = gn >> 6,  dd = gn & (DH_-1);
        f16x4 v;
        #pragma unroll
        for (int rr = 0; rr < 4; ++rr) v[rr] = (f16)(acc[nt][mt][rr] * scale);
        *(f16x4*)&dstB[((((size_t)bb*H_ + h)*T_ + t)*DH_) + dd] = v;
      }
  } else {
    // V -> [b,h,d,t] via LDS transpose bounce (coalesced 128B global stores)
    f16* VtS = (f16*)smem;              // [128][136] = 34816 B, safe after final barrier
    #pragma unroll
    for (int mt = 0; mt < 4; ++mt)
      #pragma unroll
      for (int nt = 0; nt < 4; ++nt) {
        f16x4 v;
        v[0]=(f16)acc[mt][nt][0]; v[1]=(f16)acc[mt][nt][1];
        v[2]=(f16)acc[mt][nt][2]; v[3]=(f16)acc[mt][nt][3];
        *(f16x4*)&VtS[(size_t)(wn*64 + nt*16 + ln)*136 + wm*64 + mt*16 + quad*4] = v;
      }
    __syncthreads();
    int dd_loc = tid >> 1, half = tid & 1;
    int gn = n0 + dd_loc, h = gn >> 6, dd = gn & (DH_-1);
    int bb = m0 >> 11, tb = (m0 & (T_-1)) + half*64;
    f16* dst = Vtp + ((size_t)(bb*H_ + h)*DH_ + dd)*T_ + tb;
    const f16* src = VtS + (size_t)dd_loc*136 + half*64;
    #pragma unroll
    for (int u = 0; u < 8; ++u)
      *(uint4*)(dst + u*8) = *(const uint4*)(src + u*8);
  }
}

// ---------------- flash attention: causal-paired q-tiles, uniform work per block ----------------
// grid 512: bh = fid & 31 (same head -> same XCD), p = fid >> 5 in [0,16).
// Block owns q-tiles qtA = p (light) and qtB = 31-p (heavy); per-block MFMA work is
// (p+1) + (32-p) = 33 tile-units, constant -> no straggler makespan.
// KV range of A (0..p) is a prefix of B's (0..31-p): single shared staging stream.
// 4 waves x 16 q-rows per tile; S^T no-max softmax, async dbuf K/V (64-row tiles).
__launch_bounds__(256, 3)
__global__ void flash(const f16* __restrict__ Qp, const f16* __restrict__ Kp,
                      const f16* __restrict__ Vtp, f16* __restrict__ ctx) {
  const int fid = blockIdx.x;
  const int bh = fid & 31;
  const int p  = fid >> 5;              // 0..15
  const int qtA = p, qtB = 31 - p;
  const int b = bh >> 4, h = bh & (H_-1);
  const f16* Kh = Kp  + (size_t)bh * T_ * DH_;
  const f16* Vh = Vtp + (size_t)bh * DH_ * T_;
  const f16* Qh = Qp  + (size_t)bh * T_ * DH_;
  const int tid = threadIdx.x, lane = tid & 63, w = tid >> 6;
  const int ln = lane & 15, quad = lane >> 4;
  __shared__ alignas(16) f16 Ks[2*64*64];   // dbuf, XOR-swizzled 16B blocks
  __shared__ alignas(16) f16 Vs[2*64*64];
  __shared__ alignas(16) f16 Ps[128][72];   // rows: [gq*64 + w*16 + ln]

  const int qwA = qtA*64 + w*16;
  const int qwB = qtB*64 + w*16;

  f16x8 qfA[2], qfB[2];
  #pragma unroll
  for (int ks = 0; ks < 2; ++ks) {
    qfA[ks] = *(const f16x8*)&Qh[(size_t)(qwA + ln)*DH_ + ks*32 + quad*8];
    qfB[ks] = *(const f16x8*)&Qh[(size_t)(qwB + ln)*DH_ + ks*32 + quad*8];
  }

  f32x4 oA[4], oB[4];
  #pragma unroll
  for (int dt = 0; dt < 4; ++dt) { oA[dt] = f32x4{0.f,0.f,0.f,0.f}; oB[dt] = f32x4{0.f,0.f,0.f,0.f}; }
  float lA = 0.f, lB = 0.f;

  // prologue: stage kv tile 0 into buffer 0 (256 threads, 2 slots each per array)
  #pragma unroll
  for (int i = 0; i < 2; ++i) {
    int slot = i*256 + tid;
    int row  = slot >> 3;
    int c    = (slot & 7) ^ (row & 7);
    GLOAD_LDS(Kh + (size_t)row*DH_ + c*8, Ks + (size_t)slot*8);
    GLOAD_LDS(Vh + (size_t)row*T_  + c*8, Vs + (size_t)slot*8);
  }
  __syncthreads();

  for (int it = 0; it <= qtB; ++it) {
    const f16* Kc = Ks + (it & 1)*4096;
    const f16* Vc = Vs + (it & 1)*4096;
    if (it < qtB) {    // async-prefetch next tile into other buffer
      const int kv1 = (it + 1)*64;
      f16* Kn = Ks + ((it + 1) & 1)*4096;
      f16* Vn = Vs + ((it + 1) & 1)*4096;
      #pragma unroll
      for (int i = 0; i < 2; ++i) {
        int slot = i*256 + tid;
        int row  = slot >> 3;
        int c    = (slot & 7) ^ (row & 7);
        GLOAD_LDS(Kh + (size_t)(kv1 + row)*DH_ + c*8, Kn + (size_t)slot*8);
        GLOAD_LDS(Vh + (size_t)row*T_ + kv1 + c*8,    Vn + (size_t)slot*8);
      }
    }
    const bool actA = (it <= qtA);      // block-uniform: light tile active on prefix
    const int kv0 = it*64;

    // S^T[kv][q] = mfma(K rows, Q rows); kx loads shared across both q-tiles
    f32x4 sA[4], sB[4];
    #pragma unroll
    for (int kt = 0; kt < 4; ++kt) { sA[kt] = f32x4{0.f,0.f,0.f,0.f}; sB[kt] = f32x4{0.f,0.f,0.f,0.f}; }
    #pragma unroll
    for (int ks = 0; ks < 2; ++ks) {
      f16x8 kx[4];
      #pragma unroll
      for (int kt = 0; kt < 4; ++kt)
        kx[kt] = *(const f16x8*)(Kc + (size_t)(kt*16 + ln)*64 + (((ks*4 + quad) ^ (ln & 7))*8));
      #pragma unroll
      for (int kt = 0; kt < 4; ++kt)
        sB[kt] = __builtin_amdgcn_mfma_f32_16x16x32_f16(kx[kt], qfB[ks], sB[kt], 0, 0, 0);
      if (actA) {
        #pragma unroll
        for (int kt = 0; kt < 4; ++kt)
          sA[kt] = __builtin_amdgcn_mfma_f32_16x16x32_f16(kx[kt], qfA[ks], sA[kt], 0, 0, 0);
      }
    }

    // group B: diagonal mask only at its last tile
    if (it == qtB) {
      #pragma unroll
      for (int kt = 0; kt < 4; ++kt)
        #pragma unroll
        for (int rr = 0; rr < 4; ++rr)
          if (kv0 + kt*16 + quad*4 + rr > qwB + ln) sB[kt][rr] = -INFINITY;
    }
    #pragma unroll
    for (int kt = 0; kt < 4; ++kt) {
      f16x4 pk;
      #pragma unroll
      for (int rr = 0; rr < 4; ++rr) {
        float pe = __expf(sB[kt][rr]);
        lB += pe;
        pk[rr] = (f16)pe;
      }
      *(f16x4*)&Ps[64 + w*16 + ln][kt*16 + quad*4] = pk;
    }
    if (actA) {
      if (it == qtA) {
        #pragma unroll
        for (int kt = 0; kt < 4; ++kt)
          #pragma unroll
          for (int rr = 0; rr < 4; ++rr)
            if (kv0 + kt*16 + quad*4 + rr > qwA + ln) sA[kt][rr] = -INFINITY;
      }
      #pragma unroll
      for (int kt = 0; kt < 4; ++kt) {
        f16x4 pk;
        #pragma unroll
        for (int rr = 0; rr < 4; ++rr) {
          float pe = __expf(sA[kt][rr]);
          lA += pe;
          pk[rr] = (f16)pe;
        }
        *(f16x4*)&Ps[w*16 + ln][kt*16 + quad*4] = pk;
      }
    }
    asm volatile("" ::: "memory");  // same-wave ds_write -> ds_read order

    // O[q][d] += mfma(P rows q, V^T rows d); vy loads shared across both q-tiles
    #pragma unroll
    for (int ks = 0; ks < 2; ++ks) {
      f16x8 pxB = *(const f16x8*)&Ps[64 + w*16 + ln][ks*32 + quad*8];
      f16x8 pxA;
      if (actA) pxA = *(const f16x8*)&Ps[w*16 + ln][ks*32 + quad*8];
      #pragma unroll
      for (int dt = 0; dt < 4; ++dt) {
        f16x8 vy = *(const f16x8*)(Vc + (size_t)(dt*16 + ln)*64 + (((ks*4 + quad) ^ (ln & 7))*8));
        oB[dt] = __builtin_amdgcn_mfma_f32_16x16x32_f16(pxB, vy, oB[dt], 0, 0, 0);
        if (actA) oA[dt] = __builtin_amdgcn_mfma_f32_16x16x32_f16(pxA, vy, oA[dt], 0, 0, 0);
      }
    }
    __syncthreads();     // drains vmcnt(0): prefetched tile complete; bufs safe to swap
  }

  // denominator reduce (2 shuffles per group) + normalize + write (both groups)
  #pragma unroll
  for (int gq = 0; gq < 2; ++gq) {
    float l = (gq == 0) ? lA : lB;
    const int qt = (gq == 0) ? qtA : qtB;
    l += __shfl_xor(l, 16, 64);
    l += __shfl_xor(l, 32, 64);
    float inv = 1.0f / l;
    #pragma unroll
    for (int rr = 0; rr < 4; ++rr) {
      float linv = __shfl(inv, quad*4 + rr, 64);
      int t = qt*64 + w*16 + quad*4 + rr;
      #pragma unroll
      for (int dt = 0; dt < 4; ++dt) {
        const f32x4* og = (gq == 0) ? oA : oB;
        ctx[(size_t)(b*T_ + t)*D_ + h*DH_ + dt*16 + ln] = (f16)(og[dt][rr] * linv);
      }
    }
  }
}

// ---------------- output projection GEMM + bias: dbuf + XCD swizzle ----------------
__launch_bounds__(256, 2)
__global__ void out_gemm(const f16* __restrict__ ctx, const f16* __restrict__ woT,
                         const float* __restrict__ bo, float* __restrict__ out) {
  const int fid = blockIdx.x;             // [0,256)
  const int g = fid & 7, r = fid >> 3;
  const int m0 = ((((r & 3) << 3) | g)) * 128;   // m-block % 8 == XCD
  const int n0 = (r >> 2) * 128;
  __shared__ alignas(16) f16 smem[4*128*64];     // As[2]|Bs[2]
  f16* AsF = smem;
  f16* BsF = AsF + 2*128*64;
  const int tid = threadIdx.x;
  const int lane = tid & 63, wave = tid >> 6;
  const int ln = lane & 15, quad = lane >> 4;
  const int wm = wave >> 1, wn = wave & 1;

  f32x4 acc[4][4];   // [nt][mt], C^T layout
  #pragma unroll
  for (int a=0;a<4;++a)
    #pragma unroll
    for (int b=0;b<4;++b) acc[a][b] = f32x4{0.f,0.f,0.f,0.f};

  #pragma unroll
  for (int p = 0; p < 4; ++p) {
    int slot = p*256 + tid;
    int row  = slot >> 3;
    int c    = (slot & 7) ^ (row & 7);
    GLOAD_LDS(ctx + (size_t)(m0+row)*D_ + c*8, AsF + (size_t)slot*8);
    GLOAD_LDS(woT + (size_t)(n0+row)*D_ + c*8, BsF + (size_t)slot*8);
  }
  __syncthreads();

  for (int it = 0; it < 16; ++it) {
    const f16* Ac = AsF + (it & 1)*8192;
    const f16* Bc = BsF + (it & 1)*8192;
    if (it < 15) {
      const int k1 = (it + 1) * 64;
      f16* An = AsF + ((it + 1) & 1)*8192;
      f16* Bn = BsF + ((it + 1) & 1)*8192;
      #pragma unroll
      for (int p = 0; p < 4; ++p) {
        int slot = p*256 + tid;
        int row  = slot >> 3;
        int c    = (slot & 7) ^ (row & 7);
        GLOAD_LDS(ctx + (size_t)(m0+row)*D_ + k1 + c*8, An + (size_t)slot*8);
        GLOAD_LDS(woT + (size_t)(n0+row)*D_ + k1 + c*8, Bn + (size_t)slot*8);
      }
    }
    #pragma unroll
    for (int ks = 0; ks < 2; ++ks) {
      const int cb = ((ks*4 + quad) ^ (ln & 7)) * 8;
      f16x8 af[4], bf[4];
      #pragma unroll
      for (int mt = 0; mt < 4; ++mt)
        af[mt] = *(const f16x8*)(Ac + (size_t)(wm*64 + mt*16 + ln)*64 + cb);
      #pragma unroll
      for (int nt = 0; nt < 4; ++nt)
        bf[nt] = *(const f16x8*)(Bc + (size_t)(wn*64 + nt*16 + ln)*64 + cb);
      #pragma unroll
      for (int nt = 0; nt < 4; ++nt)
        #pragma unroll
        for (int mt = 0; mt < 4; ++mt)
          acc[nt][mt] = __builtin_amdgcn_mfma_f32_16x16x32_f16(bf[nt], af[mt], acc[nt][mt], 0, 0, 0);
    }
    __syncthreads();
  }

  #pragma unroll
  for (int nt = 0; nt < 4; ++nt) {
    int gn = n0 + wn*64 + nt*16 + quad*4;
    float4 bv = *(const float4*)&bo[gn];
    #pragma unroll
    for (int mt = 0; mt < 4; ++mt) {
      int gm = m0 + wm*64 + mt*16 + ln;
      float4 v;
      v.x = acc[nt][mt][0] + bv.x;
      v.y = acc[nt][mt][1] + bv.y;
      v.z = acc[nt][mt][2] + bv.z;
      v.w = acc[nt][mt][3] + bv.w;
      *(float4*)&out[(size_t)gm*D_ + gn] = v;
    }
  }
}

extern "C" void kernel_launch(void* const* d_in, const int* in_sizes, int n_in,
                              void* d_out, int out_size, void* d_ws, size_t ws_size,
                              hipStream_t stream) {
  const float* x  = (const float*)d_in[0];
  const float* wq = (const float*)d_in[1];
  const float* wk = (const float*)d_in[2];
  const float* wv = (const float*)d_in[3];
  const float* wo = (const float*)d_in[4];
  const float* bo = (const float*)d_in[5];
  float* out = (float*)d_out;

  f16* ws    = (f16*)d_ws;
  f16* xb    = ws;                         // M_*D_
  f16* wqkvT = xb    + (size_t)M_*D_;      // 3*D_*D_
  f16* woutT = wqkvT + (size_t)3*D_*D_;    // D_*D_
  f16* Qb    = woutT + (size_t)D_*D_;      // M_*D_  ([b,h,t,d], pre-scaled)
  f16* Kb    = Qb    + (size_t)M_*D_;      // M_*D_  ([b,h,t,d])
  f16* Vb    = Kb    + (size_t)M_*D_;      // M_*D_  ([b,h,d,t])
  f16* ctx   = Vb    + (size_t)M_*D_;      // M_*D_  ([b*t, h*d])

  prep<<<6144, 256, 0, stream>>>(x, wq, wk, wv, wo, xb, wqkvT, woutT);
  qkv_gemm<<<768, 256, 0, stream>>>(xb, wqkvT, Qb, Kb, Vb);
  flash<<<512, 256, 0, stream>>>(Qb, Kb, Vb, ctx);
  out_gemm<<<256, 256, 0, stream>>>(ctx, woutT, bo, out);
}

// Round 3
// 163.321 us; speedup vs baseline: 1.0992x; 1.0877x over previous
//
#include <hip/hip_runtime.h>
#include <hip/hip_bf16.h>

#define B_  2
#define T_  2048
#define D_  1024
#define H_  16
#define DH_ 64
#define M_  (B_*T_)   // 4096

typedef _Float16 f16;
typedef __attribute__((ext_vector_type(4))) _Float16 f16x4;
typedef __attribute__((ext_vector_type(8))) _Float16 f16x8;
typedef __attribute__((ext_vector_type(4))) float f32x4;

// async global->LDS, 16B per lane; LDS dest must be wave-uniform-base + lane*16
#define GLOAD_LDS(gp, lp) __builtin_amdgcn_global_load_lds( \
    (const __attribute__((address_space(1))) void*)(gp),    \
    (__attribute__((address_space(3))) void*)(lp), 16, 0, 0)

// ---------------- prep: x fp32->fp16 convert + 4 weight transposes, one launch ----------------
__global__ void prep(const float* __restrict__ x,
                     const float* __restrict__ wq, const float* __restrict__ wk,
                     const float* __restrict__ wv, const float* __restrict__ wo,
                     f16* __restrict__ xb, f16* __restrict__ wqkvT, f16* __restrict__ woutT) {
  __shared__ float tile[32][33];
  const int bid = blockIdx.x;
  if (bid < 2048) {
    size_t i = ((size_t)bid * 256 + threadIdx.x) * 8;
    float4 a = *(const float4*)(x + i);
    float4 b = *(const float4*)(x + i + 4);
    f16x8 o;
    o[0]=(f16)a.x; o[1]=(f16)a.y; o[2]=(f16)a.z; o[3]=(f16)a.w;
    o[4]=(f16)b.x; o[5]=(f16)b.y; o[6]=(f16)b.z; o[7]=(f16)b.w;
    *(f16x8*)(xb + i) = o;
  } else {
    const int b2 = bid - 2048;
    const int j = b2 >> 10, rem = b2 & 1023;
    const float* src = (j==0)?wq:(j==1)?wk:(j==2)?wv:wo;
    f16* dst = (j<3) ? (wqkvT + (size_t)j*D_*D_) : woutT;
    const int n0 = (rem & 31)*32, k0 = (rem >> 5)*32;
    const int tx = threadIdx.x & 31, ty = threadIdx.x >> 5;  // (32,8)
    #pragma unroll
    for (int i=0;i<32;i+=8)
      tile[ty+i][tx] = src[(size_t)(k0+ty+i)*D_ + n0+tx];
    __syncthreads();
    #pragma unroll
    for (int i=0;i<32;i+=8)
      dst[(size_t)(n0+ty+i)*D_ + k0+tx] = (f16)tile[tx][ty+i];
  }
}

// ---------------- QKV projection GEMM: dbuf K-loop + XCD swizzle ----------------
__launch_bounds__(256, 2)
__global__ void qkv_gemm(const f16* __restrict__ xb, const f16* __restrict__ wT,
                         f16* __restrict__ Qp, f16* __restrict__ Kp, f16* __restrict__ Vtp) {
  const int fid = blockIdx.x;
  const int g = fid & 7, r = fid >> 3;
  const int m0 = ((((r & 3) << 3) | g)) * 128;   // 32 m-blocks; m-block % 8 == XCD
  const int n0 = ((r >> 2) & 7) * 128;           // 8 n-blocks
  const int j  = r >> 5;                         // 0..2
  const f16* B0 = wT + (size_t)j * D_ * D_;
  __shared__ alignas(16) char smem[65536];       // As[2]|Bs[2] = 64 KB; VtS reuses front
  f16* AsF = (f16*)smem;             // [2][128*64]
  f16* BsF = AsF + 2*128*64;         // [2][128*64]
  const int tid = threadIdx.x;
  const int lane = tid & 63, wave = tid >> 6;
  const int ln = lane & 15, quad = lane >> 4;
  const int wm = wave >> 1, wn = wave & 1;

  f32x4 acc[4][4];
  #pragma unroll
  for (int a=0;a<4;++a)
    #pragma unroll
    for (int b=0;b<4;++b) acc[a][b] = f32x4{0.f,0.f,0.f,0.f};

  const bool swapped = (j < 2);
  const int slot_row[4] = { (0*256+tid)>>3, (1*256+tid)>>3, (2*256+tid)>>3, (3*256+tid)>>3 };

  #pragma unroll
  for (int p = 0; p < 4; ++p) {
    int slot = p*256 + tid;
    int row  = slot_row[p];
    int c    = (slot & 7) ^ (row & 7);
    GLOAD_LDS(xb + (size_t)(m0+row)*D_ + c*8, AsF + (size_t)slot*8);
    GLOAD_LDS(B0 + (size_t)(n0+row)*D_ + c*8, BsF + (size_t)slot*8);
  }
  __syncthreads();

  for (int it = 0; it < 16; ++it) {
    const f16* Ac = AsF + (it & 1)*8192;
    const f16* Bc = BsF + (it & 1)*8192;
    if (it < 15) {   // async-prefetch next k-tile into other buffer
      const int k1 = (it + 1) * 64;
      f16* An = AsF + ((it + 1) & 1)*8192;
      f16* Bn = BsF + ((it + 1) & 1)*8192;
      #pragma unroll
      for (int p = 0; p < 4; ++p) {
        int slot = p*256 + tid;
        int row  = slot_row[p];
        int c    = (slot & 7) ^ (row & 7);
        GLOAD_LDS(xb + (size_t)(m0+row)*D_ + k1 + c*8, An + (size_t)slot*8);
        GLOAD_LDS(B0 + (size_t)(n0+row)*D_ + k1 + c*8, Bn + (size_t)slot*8);
      }
    }
    #pragma unroll
    for (int ks = 0; ks < 2; ++ks) {
      const int cb = ((ks*4 + quad) ^ (ln & 7)) * 8;
      f16x8 af[4], bf[4];
      #pragma unroll
      for (int mt = 0; mt < 4; ++mt)
        af[mt] = *(const f16x8*)(Ac + (size_t)(wm*64 + mt*16 + ln)*64 + cb);
      #pragma unroll
      for (int nt = 0; nt < 4; ++nt)
        bf[nt] = *(const f16x8*)(Bc + (size_t)(wn*64 + nt*16 + ln)*64 + cb);
      if (swapped) {
        #pragma unroll
        for (int nt = 0; nt < 4; ++nt)
          #pragma unroll
          for (int mt = 0; mt < 4; ++mt)
            acc[nt][mt] = __builtin_amdgcn_mfma_f32_16x16x32_f16(bf[nt], af[mt], acc[nt][mt], 0, 0, 0);
      } else {
        #pragma unroll
        for (int mt = 0; mt < 4; ++mt)
          #pragma unroll
          for (int nt = 0; nt < 4; ++nt)
            acc[mt][nt] = __builtin_amdgcn_mfma_f32_16x16x32_f16(af[mt], bf[nt], acc[mt][nt], 0, 0, 0);
      }
    }
    __syncthreads();   // drains vmcnt(0): prefetch done; all reads of Ac/Bc done
  }

  if (swapped) {
    // C^T: row n = wn*64+nt*16+quad*4+r (feature), col m = wm*64+mt*16+ln (token)
    // Q pre-scale folds softmax 1/8 AND log2(e) so flash can use exp2 directly.
    const float scale = (j == 0) ? (0.125f * 1.44269504088896f) : 1.0f;
    f16* dstB = (j == 0) ? Qp : Kp;
    #pragma unroll
    for (int nt = 0; nt < 4; ++nt)
      #pragma unroll
      for (int mt = 0; mt < 4; ++mt) {
        int gm = m0 + wm*64 + mt*16 + ln;            // token
        int gn = n0 + wn*64 + nt*16 + quad*4;        // feature (base of 4)
        int bb = gm >> 11, t = gm & (T_-1);
        int h  = gn >> 6,  dd = gn & (DH_-1);
        f16x4 v;
        #pragma unroll
        for (int rr = 0; rr < 4; ++rr) v[rr] = (f16)(acc[nt][mt][rr] * scale);
        *(f16x4*)&dstB[((((size_t)bb*H_ + h)*T_ + t)*DH_) + dd] = v;
      }
  } else {
    // V -> [b,h,d,t] via LDS transpose bounce (coalesced 128B global stores)
    f16* VtS = (f16*)smem;              // [128][136] = 34816 B, safe after final barrier
    #pragma unroll
    for (int mt = 0; mt < 4; ++mt)
      #pragma unroll
      for (int nt = 0; nt < 4; ++nt) {
        f16x4 v;
        v[0]=(f16)acc[mt][nt][0]; v[1]=(f16)acc[mt][nt][1];
        v[2]=(f16)acc[mt][nt][2]; v[3]=(f16)acc[mt][nt][3];
        *(f16x4*)&VtS[(size_t)(wn*64 + nt*16 + ln)*136 + wm*64 + mt*16 + quad*4] = v;
      }
    __syncthreads();
    int dd_loc = tid >> 1, half = tid & 1;
    int gn = n0 + dd_loc, h = gn >> 6, dd = gn & (DH_-1);
    int bb = m0 >> 11, tb = (m0 & (T_-1)) + half*64;
    f16* dst = Vtp + ((size_t)(bb*H_ + h)*DH_ + dd)*T_ + tb;
    const f16* src = VtS + (size_t)dd_loc*136 + half*64;
    #pragma unroll
    for (int u = 0; u < 8; ++u)
      *(uint4*)(dst + u*8) = *(const uint4*)(src + u*8);
  }
}

// ---------------- flash attention v3: kv-split waves, in-register P ----------------
// grid 1024: bh = fid & 31 (same head -> same XCD), qt = 31 - (fid >> 5) (heavy first).
// Block owns ONE 64-row q-tile; wave w owns kv rows [w*16, w*16+16) of each staged tile.
// All 64 q rows in registers (qf[4][2]). S^T fragment (kv=quad*4+rr, q=ln) is EXACTLY the
// B-operand fragment of mfma_f32_16x16x16f16 -> P never touches LDS or lanes.
// Per wave-iter LDS: K 2xb128 + V 4xb64 = 4 KB (block 16 KB = one copy of the tile).
// Each wave accumulates partial O^T[64d][64q] over its kv slice; cross-wave LDS tree at end.
__launch_bounds__(256, 3)
__global__ void flash(const f16* __restrict__ Qp, const f16* __restrict__ Kp,
                      const f16* __restrict__ Vtp, f16* __restrict__ ctx) {
  const int fid = blockIdx.x;
  const int bh = fid & 31;
  const int qt = 31 - (fid >> 5);       // heavy first
  const int b = bh >> 4, h = bh & (H_-1);
  const f16* Kh = Kp  + (size_t)bh * T_ * DH_;
  const f16* Vh = Vtp + (size_t)bh * DH_ * T_;
  const f16* Qh = Qp  + (size_t)bh * T_ * DH_;
  const int tid = threadIdx.x, lane = tid & 63, w = tid >> 6;
  const int ln = lane & 15, quad = lane >> 4;

  __shared__ alignas(16) char smem[32768];
  f16* Ks = (f16*)smem;            // [2][64][64], XOR-swizzled 16B blocks
  f16* Vs = (f16*)(smem + 16384);  // [2][64][64] (V^T rows d), same swizzle

  // Q fragments: all 64 q rows (4 groups of 16) per wave
  f16x8 qf[4][2];
  #pragma unroll
  for (int g = 0; g < 4; ++g)
    #pragma unroll
    for (int ks = 0; ks < 2; ++ks)
      qf[g][ks] = *(const f16x8*)&Qh[(size_t)(qt*64 + g*16 + ln)*DH_ + ks*32 + quad*8];

  f32x4 o[4][4];   // [dt][g]: O^T[d=dt*16+quad*4+rr][q=g*16+ln] partial over wave's kv
  #pragma unroll
  for (int dt = 0; dt < 4; ++dt)
    #pragma unroll
    for (int g = 0; g < 4; ++g) o[dt][g] = f32x4{0.f,0.f,0.f,0.f};
  float lp[4] = {0.f, 0.f, 0.f, 0.f};

  // prologue: stage kv tile 0 into buffer 0
  #pragma unroll
  for (int i = 0; i < 2; ++i) {
    int slot = i*256 + tid;
    int row  = slot >> 3;
    int c    = (slot & 7) ^ (row & 7);
    GLOAD_LDS(Kh + (size_t)row*DH_ + c*8, Ks + (size_t)slot*8);
    GLOAD_LDS(Vh + (size_t)row*T_  + c*8, Vs + (size_t)slot*8);
  }
  __syncthreads();

  for (int it = 0; it <= qt; ++it) {
    const f16* Kc = Ks + (it & 1)*4096;
    const f16* Vc = Vs + (it & 1)*4096;
    if (it < qt) {    // async-prefetch next tile into other buffer
      const int kv1 = (it + 1)*64;
      f16* Kn = Ks + ((it + 1) & 1)*4096;
      f16* Vn = Vs + ((it + 1) & 1)*4096;
      #pragma unroll
      for (int i = 0; i < 2; ++i) {
        int slot = i*256 + tid;
        int row  = slot >> 3;
        int c    = (slot & 7) ^ (row & 7);
        GLOAD_LDS(Kh + (size_t)(kv1 + row)*DH_ + c*8, Kn + (size_t)slot*8);
        GLOAD_LDS(Vh + (size_t)row*T_ + kv1 + c*8,    Vn + (size_t)slot*8);
      }
    }

    // QK^T: s[g] = S^T[kv = w*16+quad*4+rr][q = g*16+ln]
    f32x4 s[4];
    #pragma unroll
    for (int g = 0; g < 4; ++g) s[g] = f32x4{0.f,0.f,0.f,0.f};
    #pragma unroll
    for (int ks = 0; ks < 2; ++ks) {
      f16x8 kx = *(const f16x8*)(Kc + (size_t)(w*16 + ln)*64 + (((ks*4 + quad) ^ (ln & 7))*8));
      #pragma unroll
      for (int g = 0; g < 4; ++g)
        s[g] = __builtin_amdgcn_mfma_f32_16x16x32_f16(kx, qf[g][ks], s[g], 0, 0, 0);
    }

    if (it == qt) {    // diagonal tile: causal mask (kv_local > q_local)
      #pragma unroll
      for (int g = 0; g < 4; ++g)
        #pragma unroll
        for (int rr = 0; rr < 4; ++rr)
          if (w*16 + quad*4 + rr > g*16 + ln) s[g][rr] = -INFINITY;
    }

    // exp2 (Q pre-scaled by log2e) + pack to f16 + denominator partials
    f16x4 pb[4];
    #pragma unroll
    for (int g = 0; g < 4; ++g) {
      #pragma unroll
      for (int rr = 0; rr < 4; ++rr) {
        float pe = __builtin_amdgcn_exp2f(s[g][rr]);
        lp[g] += pe;
        pb[g][rr] = (f16)pe;
      }
    }

    // PV partial: o[dt][g] += V^T[d][kv-slice] * P^T[kv-slice][q], k=16 MFMA
    #pragma unroll
    for (int dt = 0; dt < 4; ++dt) {
      f16x4 vf = *(const f16x4*)(Vc + (size_t)(dt*16 + ln)*64
                   + (((2*w + (quad >> 1)) ^ (ln & 7))*8) + (quad & 1)*4);
      #pragma unroll
      for (int g = 0; g < 4; ++g)
        o[dt][g] = __builtin_amdgcn_mfma_f32_16x16x16f16(vf, pb[g], o[dt][g], 0, 0, 0);
    }
    __syncthreads();   // drains vmcnt(0): prefetched tile complete; bufs safe to swap
  }

  // quad-reduce denominator partials (each lane's lp covers its quad's 4 kv rows)
  #pragma unroll
  for (int g = 0; g < 4; ++g) {
    lp[g] += __shfl_xor(lp[g], 16, 64);
    lp[g] += __shfl_xor(lp[g], 32, 64);
  }

  // cross-wave reduction tree in LDS (reuse Ks/Vs region): buf[65][68] f32 (O^T rows 0..63, l row 64)
  float* buf = (float*)smem;
  #define WR_PART() do {                                                        \
    _Pragma("unroll")                                                           \
    for (int dt = 0; dt < 4; ++dt)                                              \
      _Pragma("unroll")                                                         \
      for (int g = 0; g < 4; ++g)                                               \
        *(f32x4*)&buf[(size_t)(g*16 + ln)*68 + dt*16 + quad*4] = o[dt][g];      \
    if (quad == 0) {                                                            \
      _Pragma("unroll")                                                         \
      for (int g = 0; g < 4; ++g) buf[64*68 + g*16 + ln] = lp[g];               \
    }                                                                           \
  } while (0)
  #define ACC_PART() do {                                                       \
    _Pragma("unroll")                                                           \
    for (int dt = 0; dt < 4; ++dt)                                              \
      _Pragma("unroll")                                                         \
      for (int g = 0; g < 4; ++g) {                                             \
        f32x4 v = *(const f32x4*)&buf[(size_t)(g*16 + ln)*68 + dt*16 + quad*4]; \
        o[dt][g][0] += v[0]; o[dt][g][1] += v[1];                               \
        o[dt][g][2] += v[2]; o[dt][g][3] += v[3];                               \
      }                                                                         \
    _Pragma("unroll")                                                           \
    for (int g = 0; g < 4; ++g) lp[g] += buf[64*68 + g*16 + ln];                \
  } while (0)

  if (w == 1) WR_PART();
  __syncthreads();
  if (w == 0) ACC_PART();
  __syncthreads();
  if (w == 2) WR_PART();
  __syncthreads();
  if (w == 0) ACC_PART();
  __syncthreads();
  if (w == 3) WR_PART();
  __syncthreads();
  if (w == 0) ACC_PART();
  __syncthreads();
  if (w == 0) WR_PART();   // publish fully-reduced O^T + l
  __syncthreads();

  // normalized coalesced output: thread -> (q = tid>>2, 16-d chunk)
  {
    const int q  = tid >> 2;
    const int dc = (tid & 3) << 4;
    const float linv = 1.0f / buf[64*68 + q];
    const float* src = &buf[(size_t)q*68 + dc];
    f16x8 o0, o1;
    #pragma unroll
    for (int jj = 0; jj < 8; ++jj) {
      o0[jj] = (f16)(src[jj] * linv);
      o1[jj] = (f16)(src[8 + jj] * linv);
    }
    f16* dst = &ctx[(size_t)(b*T_ + qt*64 + q)*D_ + h*DH_ + dc];
    *(f16x8*)dst       = o0;
    *(f16x8*)(dst + 8) = o1;
  }
  #undef WR_PART
  #undef ACC_PART
}

// ---------------- output projection GEMM + bias: dbuf + XCD swizzle ----------------
__launch_bounds__(256, 2)
__global__ void out_gemm(const f16* __restrict__ ctx, const f16* __restrict__ woT,
                         const float* __restrict__ bo, float* __restrict__ out) {
  const int fid = blockIdx.x;             // [0,256)
  const int g = fid & 7, r = fid >> 3;
  const int m0 = ((((r & 3) << 3) | g)) * 128;   // m-block % 8 == XCD
  const int n0 = (r >> 2) * 128;
  __shared__ alignas(16) f16 smem[4*128*64];     // As[2]|Bs[2]
  f16* AsF = smem;
  f16* BsF = AsF + 2*128*64;
  const int tid = threadIdx.x;
  const int lane = tid & 63, wave = tid >> 6;
  const int ln = lane & 15, quad = lane >> 4;
  const int wm = wave >> 1, wn = wave & 1;

  f32x4 acc[4][4];   // [nt][mt], C^T layout
  #pragma unroll
  for (int a=0;a<4;++a)
    #pragma unroll
    for (int b=0;b<4;++b) acc[a][b] = f32x4{0.f,0.f,0.f,0.f};

  #pragma unroll
  for (int p = 0; p < 4; ++p) {
    int slot = p*256 + tid;
    int row  = slot >> 3;
    int c    = (slot & 7) ^ (row & 7);
    GLOAD_LDS(ctx + (size_t)(m0+row)*D_ + c*8, AsF + (size_t)slot*8);
    GLOAD_LDS(woT + (size_t)(n0+row)*D_ + c*8, BsF + (size_t)slot*8);
  }
  __syncthreads();

  for (int it = 0; it < 16; ++it) {
    const f16* Ac = AsF + (it & 1)*8192;
    const f16* Bc = BsF + (it & 1)*8192;
    if (it < 15) {
      const int k1 = (it + 1) * 64;
      f16* An = AsF + ((it + 1) & 1)*8192;
      f16* Bn = BsF + ((it + 1) & 1)*8192;
      #pragma unroll
      for (int p = 0; p < 4; ++p) {
        int slot = p*256 + tid;
        int row  = slot >> 3;
        int c    = (slot & 7) ^ (row & 7);
        GLOAD_LDS(ctx + (size_t)(m0+row)*D_ + k1 + c*8, An + (size_t)slot*8);
        GLOAD_LDS(woT + (size_t)(n0+row)*D_ + k1 + c*8, Bn + (size_t)slot*8);
      }
    }
    #pragma unroll
    for (int ks = 0; ks < 2; ++ks) {
      const int cb = ((ks*4 + quad) ^ (ln & 7)) * 8;
      f16x8 af[4], bf[4];
      #pragma unroll
      for (int mt = 0; mt < 4; ++mt)
        af[mt] = *(const f16x8*)(Ac + (size_t)(wm*64 + mt*16 + ln)*64 + cb);
      #pragma unroll
      for (int nt = 0; nt < 4; ++nt)
        bf[nt] = *(const f16x8*)(Bc + (size_t)(wn*64 + nt*16 + ln)*64 + cb);
      #pragma unroll
      for (int nt = 0; nt < 4; ++nt)
        #pragma unroll
        for (int mt = 0; mt < 4; ++mt)
          acc[nt][mt] = __builtin_amdgcn_mfma_f32_16x16x32_f16(bf[nt], af[mt], acc[nt][mt], 0, 0, 0);
    }
    __syncthreads();
  }

  #pragma unroll
  for (int nt = 0; nt < 4; ++nt) {
    int gn = n0 + wn*64 + nt*16 + quad*4;
    float4 bv = *(const float4*)&bo[gn];
    #pragma unroll
    for (int mt = 0; mt < 4; ++mt) {
      int gm = m0 + wm*64 + mt*16 + ln;
      float4 v;
      v.x = acc[nt][mt][0] + bv.x;
      v.y = acc[nt][mt][1] + bv.y;
      v.z = acc[nt][mt][2] + bv.z;
      v.w = acc[nt][mt][3] + bv.w;
      *(float4*)&out[(size_t)gm*D_ + gn] = v;
    }
  }
}

extern "C" void kernel_launch(void* const* d_in, const int* in_sizes, int n_in,
                              void* d_out, int out_size, void* d_ws, size_t ws_size,
                              hipStream_t stream) {
  const float* x  = (const float*)d_in[0];
  const float* wq = (const float*)d_in[1];
  const float* wk = (const float*)d_in[2];
  const float* wv = (const float*)d_in[3];
  const float* wo = (const float*)d_in[4];
  const float* bo = (const float*)d_in[5];
  float* out = (float*)d_out;

  f16* ws    = (f16*)d_ws;
  f16* xb    = ws;                         // M_*D_
  f16* wqkvT = xb    + (size_t)M_*D_;      // 3*D_*D_
  f16* woutT = wqkvT + (size_t)3*D_*D_;    // D_*D_
  f16* Qb    = woutT + (size_t)D_*D_;      // M_*D_  ([b,h,t,d], pre-scaled by 0.125*log2e)
  f16* Kb    = Qb    + (size_t)M_*D_;      // M_*D_  ([b,h,t,d])
  f16* Vb    = Kb    + (size_t)M_*D_;      // M_*D_  ([b,h,d,t])
  f16* ctx   = Vb    + (size_t)M_*D_;      // M_*D_  ([b*t, h*d])

  prep<<<6144, 256, 0, stream>>>(x, wq, wk, wv, wo, xb, wqkvT, woutT);
  qkv_gemm<<<768, 256, 0, stream>>>(xb, wqkvT, Qb, Kb, Vb);
  flash<<<1024, 256, 0, stream>>>(Qb, Kb, Vb, ctx);
  out_gemm<<<256, 256, 0, stream>>>(ctx, woutT, bo, out);
}